// Round 8
// baseline (3351.688 us; speedup 1.0000x reference)
//
#include <hip/hip_runtime.h>
#include <math.h>

// ---------------- problem constants ----------------
#define BB 32768
#define LL 24
#define HH 128
#define ZZ 32
#define ROWS 64
#define NTHR 512
#define NBLK (BB/ROWS)

typedef __attribute__((ext_vector_type(8))) short bf16x8;
typedef __attribute__((ext_vector_type(4))) float f32x4;
#define MFMA16(a,b,c) __builtin_amdgcn_mfma_f32_16x16x32_bf16(a,b,c,0,0,0)

// ---------------- LDS byte offsets (total 161936 <= 163840) ----------------
#define STG   0        // 32768: staged B-weight [128][128] bf16 (XOR swizzled)
#define HB    32768    // 16384: h   [64][128] bf16 XOR
#define CONDB 49152    // 16384: cond(bf16) / i1(prologue)
#define AB    65536    // 16384: i3 / relu1 / d1 bf16 XOR
#define ZB    81920    // 5120:  z [64 rows][stride 80B] bf16 (K=32)
#define DW1BT 87040    // 10240: dw1b^T [128][stride 80B] bf16 resident
#define PW1T  97280    // 8192:  pw1^T [32][128] bf16 XOR resident
#define WFUT  105472   // 8192:  Wfuse^T resident
#define EW3BT 113664   // 8192:  ew3b^T resident
#define MVW   121856   // 16384: pwm,pwv,ewm,ewv f32 [32][32] each
#define SAB   138240   // 17408: SA=ph [32col][68row] f32; SB=+8704 inter; D2 overlay [64][68]
#define KOB   SAB      // 8704:  outK step-tile [64 rows][stride 34 f32] (overlays dead ph, C8..P6)
#define GTB   155648   // 1088:  gt [4][68] f32
#define BXB   156736   // 1088:  bbox [4][68] f32
#define PERMB 157824   // 4112:  ew1 f32@0, eb1@2048, dw3@2560, db3@3584, pbm@3600, pbv@3728, ebm@3856, ebv@3984
#define LDS_BYTES 161936

// ---------------- ws (global scratch) byte offsets ----------------
#define W_VECB 0           // f32 [24][128]
#define W_BFU  12288       // f32 [32]
#define WB     12416
#define W_CW2T  (WB+0)       // [128][128] bf16 packed (all *T are [N][K])
#define W_CWOAT (WB+32768)
#define W_CW5T  (WB+65536)
#define W_CWOCT (WB+98304)
#define W_DW1AT (WB+131072)
#define W_DW2T  (WB+163840)  // [64][128]
#define W_LRT   (WB+180224)  // [512][128]
#define W_PW1T  (WB+311296)  // [32][128]
#define W_WFUT  (WB+319488)
#define W_EW3BT (WB+327680)
#define W_DW1BT (WB+335872)  // [128][32]

__device__ __forceinline__ float sigf(float x){ return 1.0f/(1.0f+__expf(-x)); }
__device__ __forceinline__ float tanhf_(float x){ return 2.0f/(1.0f+__expf(-2.0f*x)) - 1.0f; }
__device__ __forceinline__ ushort f2b(float f){
  union{float f; unsigned u;} x; x.f = f;
  unsigned r = x.u + 0x7FFFu + ((x.u>>16)&1u);
  return (ushort)(r>>16);
}

// A/B fragment load from XOR-swizzled [idx][128] bf16 buffer (256B row stride)
__device__ __forceinline__ bf16x8 ldfrag(const char* sm, int base, int idx, int kk, int lch){
  int b = idx*256 + kk*64 + lch*16;
  b ^= (idx&7)<<4;
  return *(const bf16x8*)(sm + base + b);
}
// fragment load from stride-80B K<=32 buffer (no swizzle; pad-based spread)
__device__ __forceinline__ bf16x8 ldfragP(const char* sm, int base, int idx, int lch){
  return *(const bf16x8*)(sm + base + idx*80 + lch*16);
}
// scalar bf16 store into XOR-swizzled A-buffer
__device__ __forceinline__ void stb16(char* sm, int base, int row, int col, ushort v){
  int b = row*256 + col*2;
  b ^= (row&7)<<4;
  *(ushort*)(sm + base + b) = v;
}
// paired bf16 store (col even)
__device__ __forceinline__ void stb32(char* sm, int base, int row, int col, unsigned v){
  int b = row*256 + col*2;
  b ^= (row&7)<<4;
  *(unsigned*)(sm + base + b) = v;
}

// staged-weight copy helpers: issue loads early (regs), write late (XOR layout)
template<int NR>
__device__ __forceinline__ void stg_issue(const char* __restrict__ src, int tid, uint4* r){
  #pragma unroll
  for (int i = 0; i < NR*16/NTHR; ++i)
    r[i] = *(const uint4*)(src + (tid + i*NTHR)*16);
}
template<int NR>
__device__ __forceinline__ void stg_write(char* sm, int tid, const uint4* r){
  #pragma unroll
  for (int i = 0; i < NR*16/NTHR; ++i){
    int idx = tid + i*NTHR;
    int row = idx >> 4, ch = idx & 15;
    *(uint4*)(sm + STG + row*256 + ((ch*16) ^ ((row&7)<<4))) = r[i];
  }
}

// ---------------- setup kernel ----------------
__global__ void vae_pre(const float* __restrict__ cw2,
                        const float* __restrict__ cw3, const float* __restrict__ cb3,
                        const float* __restrict__ cw4, const float* __restrict__ cb4,
                        const float* __restrict__ cw5,
                        const float* __restrict__ cwo,
                        const float* __restrict__ pw1,
                        const float* __restrict__ ew2, const float* __restrict__ ew3,
                        const float* __restrict__ eb2, const float* __restrict__ eb3,
                        const float* __restrict__ dw1, const float* __restrict__ dw2,
                        const float* __restrict__ lr,
                        char* __restrict__ ws)
{
  const int tid = threadIdx.x;
  if (blockIdx.x == 0) {
    __shared__ float t1[24][129];
    __shared__ float t2[24][129];
    for (int idx = tid; idx < 24*128; idx += 256) {
      int tt = idx >> 7, j = idx & 127;
      t1[tt][j] = fmaxf(cw3[tt*HH + j] + cb3[j], 0.f);
    }
    __syncthreads();
    for (int idx = tid; idx < 24*128; idx += 256) {
      int tt = idx >> 7, j = idx & 127;
      float a = cb4[j];
      for (int k = 0; k < 128; ++k) a = fmaf(t1[tt][k], cw4[k*HH + j], a);
      t2[tt][j] = fmaxf(a, 0.f);
    }
    __syncthreads();
    float* vecB = (float*)(ws + W_VECB);
    for (int idx = tid; idx < 24*128; idx += 256) {
      int tt = idx >> 7, j = idx & 127;
      float a = 0.f;
      for (int k = 0; k < 128; ++k) a = fmaf(t2[tt][k], cwo[(128+k)*HH + j], a);
      vecB[tt*HH + j] = a;
    }
    ushort* wfut = (ushort*)(ws + W_WFUT);       // [32][128]: wfut[n*128+k] = Wfuse[k][n]
    for (int idx = tid; idx < 128*32; idx += 256) {
      int k = idx >> 5, n = idx & 31;
      float a = 0.f;
      for (int kk = 0; kk < 128; ++kk) a = fmaf(ew2[k*HH + kk], ew3[kk*ZZ + n], a);
      wfut[n*128 + k] = f2b(a);
    }
    if (tid < 32) {
      float a = eb3[tid];
      for (int kk = 0; kk < 128; ++kk) a = fmaf(eb2[kk], ew3[kk*ZZ + tid], a);
      *(float*)(ws + W_BFU + tid*4) = a;
    }
  } else {
    int u = blockIdx.x - 1;   // 0..40, each = 4096 dst elems
    const float* src; char* dst; int K, N, uo;
    if      (u < 4)  { src = cw2;            dst = ws+W_CW2T;  K=128; N=128; uo = u;    }
    else if (u < 8)  { src = cwo;            dst = ws+W_CWOAT; K=128; N=128; uo = u-4;  }
    else if (u < 12) { src = cw5;            dst = ws+W_CW5T;  K=128; N=128; uo = u-8;  }
    else if (u < 16) { src = cwo + 256*128;  dst = ws+W_CWOCT; K=128; N=128; uo = u-12; }
    else if (u < 20) { src = dw1;            dst = ws+W_DW1AT; K=128; N=128; uo = u-16; }
    else if (u < 22) { src = dw2;            dst = ws+W_DW2T;  K=128; N=64;  uo = u-20; }
    else if (u < 38) { src = lr;             dst = ws+W_LRT;   K=128; N=512; uo = u-22; }
    else if (u == 38){ src = pw1;            dst = ws+W_PW1T;  K=128; N=32;  uo = 0;    }
    else if (u == 39){ src = ew3 + 128*32;   dst = ws+W_EW3BT; K=128; N=32;  uo = 0;    }
    else             { src = dw1 + 128*128;  dst = ws+W_DW1BT; K=32;  N=128; uo = 0;    }
    ushort* d = (ushort*)dst;
    for (int e = uo*4096 + tid; e < uo*4096 + 4096; e += 256) {
      int n = e / K, k = e - n*K;
      d[e] = f2b(src[k*N + n]);
    }
  }
}

// ---------------- main kernel ----------------
__global__ void __launch_bounds__(NTHR, 1) vae_main(
  const float* __restrict__ ls, const float* __restrict__ bbin, const float* __restrict__ eps,
  const float* __restrict__ cw1, const float* __restrict__ cb1, const float* __restrict__ cb2,
  const float* __restrict__ cb5, const float* __restrict__ cbo,
  const float* __restrict__ pb1, const float* __restrict__ pbm, const float* __restrict__ pbv,
  const float* __restrict__ pwm, const float* __restrict__ pwv,
  const float* __restrict__ ew1, const float* __restrict__ eb1,
  const float* __restrict__ ewm, const float* __restrict__ ebm,
  const float* __restrict__ ewv, const float* __restrict__ ebv,
  const float* __restrict__ db1, const float* __restrict__ db2,
  const float* __restrict__ dw3, const float* __restrict__ db3,
  const float* __restrict__ lk, const float* __restrict__ lb,
  const char* __restrict__ ws,
  float* __restrict__ outB, float* __restrict__ outK)
{
  extern __shared__ char sm[];
  const int tid = threadIdx.x;
  const int lane = tid & 63;
  const int wv   = tid >> 6;
  const int l15  = lane & 15;
  const int lch  = lane >> 4;
  const int rt   = wv & 3;            // row tile
  const int cg   = wv >> 2;           // col half
  const int ctS  = wv >> 2;
  const int colS = ctS*16 + l15;
  const int c7b  = (wv>>2)*32;
  const int ju   = wv*16 + l15;
  const int rS   = tid & 63;
  const int cq   = tid >> 6;
  const int c0s  = cq * 4;
  const int rbase = blockIdx.x * ROWS;

  const float* vecB = (const float*)(ws + W_VECB);

  // ---------------- prologue: resident LDS + bias regs ----------------
  for (int i = tid; i < 16384/16; i += NTHR)
    *(uint4*)(sm + HB + i*16) = (uint4){0,0,0,0};
  {
    const char* srcs[3] = { ws+W_PW1T, ws+W_WFUT, ws+W_EW3BT };
    const int dsts[3] = { PW1T, WFUT, EW3BT };
    #pragma unroll
    for (int s = 0; s < 3; ++s)
      for (int i = tid; i < 512; i += NTHR) {
        int row = i >> 4, ch = i & 15;
        *(uint4*)(sm + dsts[s] + row*256 + ((ch*16) ^ ((row&7)<<4))) =
            *(const uint4*)(srcs[s] + i*16);
      }
  }
  for (int i = tid; i < 512; i += NTHR) {
    int row = i >> 2, ch = i & 3;
    *(uint4*)(sm + DW1BT + row*80 + ch*16) = *(const uint4*)(ws + W_DW1BT + row*64 + ch*16);
  }
  for (int i = tid; i < 4096; i += NTHR) {
    int w = i >> 10, j = i & 1023;
    const float* s = (w==0)?pwm:(w==1)?pwv:(w==2)?ewm:ewv;
    ((float*)(sm + MVW))[i] = s[j];
  }
  {
    float* P = (float*)(sm + PERMB);
    for (int i = tid; i < 512; i += NTHR) P[i] = ew1[i];
    for (int i = tid; i < 128; i += NTHR) P[512 + i] = eb1[i];
    for (int i = tid; i < 256; i += NTHR) P[640 + i] = dw3[i];
    if (tid < 4)  P[896 + tid] = db3[tid];
    if (tid < 32) { P[900+tid] = pbm[tid]; P[932+tid] = pbv[tid]; P[964+tid] = ebm[tid]; P[996+tid] = ebv[tid]; }
  }
  for (int i = tid; i < 24*64; i += NTHR) {
    int k = i >> 6, rr = i & 63;
    *(float*)(sm + SAB + k*272 + rr*4) = ls[(size_t)(rbase+rr)*LL + k];
  }
  float cb5r[4], db1r[4], cb2r[4], cbor[4];
  #pragma unroll
  for (int ct = 0; ct < 4; ++ct) {
    int c = cg*64 + ct*16 + l15;
    cb5r[ct] = cb5[c]; db1r[ct] = db1[c]; cb2r[ct] = cb2[c]; cbor[ct] = cbo[c];
  }
  float db2r[2]; db2r[0] = db2[c7b + l15]; db2r[1] = db2[c7b + 16 + l15];
  const float pb1r = pb1[colS];
  const float bfr  = *(const float*)(ws + W_BFU + colS*4);
  float lbr[4], lkbr[4][4];
  #pragma unroll
  for (int g = 0; g < 4; ++g) {
    lbr[g] = lb[g*128 + ju];
    #pragma unroll
    for (int k = 0; k < 4; ++k) lkbr[k][g] = lk[(24+k)*512 + g*128 + ju];
  }
  f32x4 creg[4];
  #pragma unroll
  for (int i = 0; i < 4; ++i) creg[i] = (f32x4){0.f,0.f,0.f,0.f};

  uint4 sreg[4];
  stg_issue<128>(ws + W_CW2T, tid, sreg);
  __syncthreads();

  // T1 = relu(ls@cw1+cb1) -> AB (fp32, K=24)
  {
    const int r3 = tid >> 3, cb = (tid & 7) * 16;
    float a3[16];
    #pragma unroll
    for (int c = 0; c < 16; ++c) a3[c] = cb1[cb + c];
    for (int k = 0; k < 24; ++k) {
      float g = *(const float*)(sm + SAB + k*272 + r3*4);
      #pragma unroll
      for (int c = 0; c < 16; ++c) a3[c] = fmaf(g, cw1[k*128 + cb + c], a3[c]);
    }
    #pragma unroll
    for (int c = 0; c < 16; c += 2) {
      unsigned v = (unsigned)f2b(fmaxf(a3[c],0.f)) | ((unsigned)f2b(fmaxf(a3[c+1],0.f)) << 16);
      stb32(sm, AB, r3, cb + c, v);
    }
  }
  __syncthreads();
  stg_write<128>(sm, tid, sreg);            // cw2t
  stg_issue<128>(ws + W_CWOAT, tid, sreg);
  __syncthreads();
  // i1 = relu(T1@cw2t + cb2) -> CONDB
  {
    f32x4 o[4];
    #pragma unroll
    for (int ct = 0; ct < 4; ++ct) o[ct] = (f32x4){cb2r[ct],cb2r[ct],cb2r[ct],cb2r[ct]};
    #pragma unroll
    for (int kk = 0; kk < 4; ++kk) {
      bf16x8 av = ldfrag(sm, AB, rt*16+l15, kk, lch);
      #pragma unroll
      for (int ct = 0; ct < 4; ++ct)
        o[ct] = MFMA16(av, ldfrag(sm, STG, cg*64+ct*16+l15, kk, lch), o[ct]);
    }
    #pragma unroll
    for (int ct = 0; ct < 4; ++ct)
      #pragma unroll
      for (int r = 0; r < 4; ++r)
        stb16(sm, CONDB, rt*16+lch*4+r, cg*64+ct*16+l15, f2b(fmaxf(o[ct][r],0.f)));
  }
  __syncthreads();
  stg_write<128>(sm, tid, sreg);            // cwoAt
  stg_issue<128>(ws + W_CW5T, tid, sreg);
  __syncthreads();
  // caF = i1@cwoAt + cbo
  f32x4 caF[4];
  #pragma unroll
  for (int ct = 0; ct < 4; ++ct) caF[ct] = (f32x4){cbor[ct],cbor[ct],cbor[ct],cbor[ct]};
  #pragma unroll
  for (int kk = 0; kk < 4; ++kk) {
    bf16x8 av = ldfrag(sm, CONDB, rt*16+l15, kk, lch);
    #pragma unroll
    for (int ct = 0; ct < 4; ++ct)
      caF[ct] = MFMA16(av, ldfrag(sm, STG, cg*64+ct*16+l15, kk, lch), caF[ct]);
  }

  // ---------------- 24 steps ----------------
  for (int st = 0; st < LL; ++st) {
    // per-step register prefetches (nontemporal: read-once streams, keep out of L2)
    float gtreg = 0.f;
    if (tid < 256) gtreg = __builtin_nontemporal_load(&bbin[(((size_t)rbase + rS)*LL + st)*4 + cq]);
    const f32x4 epv = __builtin_nontemporal_load((const f32x4*)&eps[(((size_t)rbase + rS)*LL + st)*ZZ + c0s]);
    float lkr[4];
    #pragma unroll
    for (int g = 0; g < 4; ++g) lkr[g] = lk[st*512 + g*128 + ju];
    float vbr[4];
    #pragma unroll
    for (int ct = 0; ct < 4; ++ct) vbr[ct] = vecB[st*128 + cg*64 + ct*16 + l15];

    __syncthreads();                          // (a)
    stg_write<128>(sm, tid, sreg);            // cw5t
    stg_issue<128>(ws + W_CWOCT, tid, sreg);
    if (tid < 256) *(float*)(sm + GTB + cq*272 + rS*4) = gtreg;
    __syncthreads();                          // (b)
    // P1: i3 = relu(h@cw5 + cb5) -> AB
    {
      f32x4 o[4];
      #pragma unroll
      for (int ct = 0; ct < 4; ++ct) o[ct] = (f32x4){cb5r[ct],cb5r[ct],cb5r[ct],cb5r[ct]};
      #pragma unroll
      for (int kk = 0; kk < 4; ++kk) {
        bf16x8 av = ldfrag(sm, HB, rt*16+l15, kk, lch);
        #pragma unroll
        for (int ct = 0; ct < 4; ++ct)
          o[ct] = MFMA16(av, ldfrag(sm, STG, cg*64+ct*16+l15, kk, lch), o[ct]);
      }
      #pragma unroll
      for (int ct = 0; ct < 4; ++ct)
        #pragma unroll
        for (int r = 0; r < 4; ++r)
          stb16(sm, AB, rt*16+lch*4+r, cg*64+ct*16+l15, f2b(fmaxf(o[ct][r],0.f)));
    }
    __syncthreads();                          // (c)
    stg_write<128>(sm, tid, sreg);            // cwoCt
    stg_issue<128>(ws + W_DW1AT, tid, sreg);
    __syncthreads();                          // (d)
    // P2: cond = i3@cwoC + caF + vecB -> CONDB
    {
      f32x4 o[4];
      #pragma unroll
      for (int ct = 0; ct < 4; ++ct) {
        o[ct] = caF[ct];
        #pragma unroll
        for (int r = 0; r < 4; ++r) o[ct][r] += vbr[ct];
      }
      #pragma unroll
      for (int kk = 0; kk < 4; ++kk) {
        bf16x8 av = ldfrag(sm, AB, rt*16+l15, kk, lch);
        #pragma unroll
        for (int ct = 0; ct < 4; ++ct)
          o[ct] = MFMA16(av, ldfrag(sm, STG, cg*64+ct*16+l15, kk, lch), o[ct]);
      }
      #pragma unroll
      for (int ct = 0; ct < 4; ++ct)
        #pragma unroll
        for (int r = 0; r < 4; ++r)
          stb16(sm, CONDB, rt*16+lch*4+r, cg*64+ct*16+l15, f2b(o[ct][r]));
    }
    __syncthreads();                          // (e)
    stg_write<128>(sm, tid, sreg);            // dw1at
    stg_issue<64>(ws + W_DW2T, tid, sreg);
    // P3a: relu1 = relu(gt@ew1 + eb1) -> AB (fp32, K=4)
    {
      const float* P = (const float*)(sm + PERMB);
      const int r3 = tid >> 3, cb = (tid & 7) * 16;
      float a3[16];
      #pragma unroll
      for (int c = 0; c < 16; ++c) a3[c] = P[512 + cb + c];
      #pragma unroll
      for (int k = 0; k < 4; ++k) {
        float g = *(const float*)(sm + GTB + k*272 + r3*4);
        #pragma unroll
        for (int c = 0; c < 16; ++c) a3[c] = fmaf(g, P[k*128 + cb + c], a3[c]);
      }
      #pragma unroll
      for (int c = 0; c < 16; c += 2) {
        unsigned v = (unsigned)f2b(fmaxf(a3[c],0.f)) | ((unsigned)f2b(fmaxf(a3[c+1],0.f)) << 16);
        stb32(sm, AB, r3, cb + c, v);
      }
    }
    // C5b: ph = relu(cond@pw1 + pb1) -> SA
    {
      f32x4 ph = (f32x4){pb1r,pb1r,pb1r,pb1r};
      #pragma unroll
      for (int kk = 0; kk < 4; ++kk)
        ph = MFMA16(ldfrag(sm, CONDB, rt*16+l15, kk, lch),
                    ldfrag(sm, PW1T, colS, kk, lch), ph);
      f32x4 v;
      #pragma unroll
      for (int r = 0; r < 4; ++r) v[r] = fmaxf(ph[r], 0.f);
      *(f32x4*)(sm + SAB + colS*272 + (rt*16+lch*4)*4) = v;
    }
    __syncthreads();                          // (f)
    // C7: inter = relu(relu1@Wfuse + cond@ew3b + bfuse) -> SB
    {
      f32x4 iv = (f32x4){bfr,bfr,bfr,bfr};
      #pragma unroll
      for (int kk = 0; kk < 4; ++kk)
        iv = MFMA16(ldfrag(sm, AB, rt*16+l15, kk, lch),
                    ldfrag(sm, WFUT, colS, kk, lch), iv);
      #pragma unroll
      for (int kk = 0; kk < 4; ++kk)
        iv = MFMA16(ldfrag(sm, CONDB, rt*16+l15, kk, lch),
                    ldfrag(sm, EW3BT, colS, kk, lch), iv);
      f32x4 v;
      #pragma unroll
      for (int r = 0; r < 4; ++r) v[r] = fmaxf(iv[r], 0.f);
      *(f32x4*)(sm + SAB + 8704 + colS*272 + (rt*16+lch*4)*4) = v;
    }
    // C6: zmc,zvc (fp32 regs) — reads SA(ph) written before barrier (f)
    float zmc[4], zvc[4];
    {
      const float* P = (const float*)(sm + PERMB);
      #pragma unroll
      for (int i = 0; i < 4; ++i) { zmc[i] = P[900 + c0s + i]; zvc[i] = P[932 + c0s + i]; }
      #pragma unroll 8
      for (int k = 0; k < 32; ++k) {
        float a = *(const float*)(sm + SAB + k*272 + rS*4);
        f32x4 wm = *(const f32x4*)(sm + MVW + k*128 + c0s*4);
        f32x4 wq = *(const f32x4*)(sm + MVW + 4096 + k*128 + c0s*4);
        #pragma unroll
        for (int i = 0; i < 4; ++i) { zmc[i] = fmaf(a, wm[i], zmc[i]); zvc[i] = fmaf(a, wq[i], zvc[i]); }
      }
    }
    __syncthreads();                          // (g)
    // C8: zm/zv, kl -> KOB (LDS), z -> ZB   [ph region dead -> KOB overlay]
    {
      const float* P = (const float*)(sm + PERMB);
      float zm[4], zv[4];
      #pragma unroll
      for (int i = 0; i < 4; ++i) { zm[i] = P[964 + c0s + i]; zv[i] = P[996 + c0s + i]; }
      #pragma unroll 8
      for (int k = 0; k < 32; ++k) {
        float a = *(const float*)(sm + SAB + 8704 + k*272 + rS*4);
        f32x4 wm = *(const f32x4*)(sm + MVW + 8192 + k*128 + c0s*4);
        f32x4 wq = *(const f32x4*)(sm + MVW + 12288 + k*128 + c0s*4);
        #pragma unroll
        for (int i = 0; i < 4; ++i) { zm[i] = fmaf(a, wm[i], zm[i]); zv[i] = fmaf(a, wq[i], zv[i]); }
      }
      f32x4 ko; unsigned zp[2];
      #pragma unroll
      for (int i = 0; i < 4; ++i) {
        float d = zm[i] - zmc[i];
        ko[i] = 0.5f*(zvc[i] - zv[i] + (__expf(zv[i]) + d*d)*__expf(-zvc[i]) - 1.0f);
        float zval = zm[i] + __expf(0.5f*zv[i]) * epv[i];
        ushort h = f2b(zval);
        if ((i&1)==0) zp[i>>1] = h; else zp[i>>1] |= ((unsigned)h)<<16;
      }
      *(f32x4*)(sm + KOB + rS*136 + c0s*4) = ko;      // stride 34 floats
      *(uint2*)(sm + ZB + rS*80 + c0s*2) = make_uint2(zp[0], zp[1]);
    }
    __syncthreads();                          // (h) zb + KOB ready, dw1at staged
    // KO write-out: full 128B lines, nontemporal (no write-allocate)
    {
      const int row = tid >> 3, colq = tid & 7;
      const f32x4 kv = *(const f32x4*)(sm + KOB + row*136 + colq*16);
      __builtin_nontemporal_store(kv,
          (f32x4*)&outK[(((size_t)rbase + row)*LL + st)*ZZ + colq*4]);
    }
    // P6: d1 = relu(cond@dw1a + z@dw1b + db1) -> AB
    {
      f32x4 o[4];
      #pragma unroll
      for (int ct = 0; ct < 4; ++ct) o[ct] = (f32x4){db1r[ct],db1r[ct],db1r[ct],db1r[ct]};
      #pragma unroll
      for (int kk = 0; kk < 4; ++kk) {
        bf16x8 av = ldfrag(sm, CONDB, rt*16+l15, kk, lch);
        #pragma unroll
        for (int ct = 0; ct < 4; ++ct)
          o[ct] = MFMA16(av, ldfrag(sm, STG, cg*64+ct*16+l15, kk, lch), o[ct]);
      }
      bf16x8 azv = ldfragP(sm, ZB, rt*16+l15, lch);
      #pragma unroll
      for (int ct = 0; ct < 4; ++ct)
        o[ct] = MFMA16(azv, ldfragP(sm, DW1BT, cg*64+ct*16+l15, lch), o[ct]);
      #pragma unroll
      for (int ct = 0; ct < 4; ++ct)
        #pragma unroll
        for (int r = 0; r < 4; ++r)
          stb16(sm, AB, rt*16+lch*4+r, cg*64+ct*16+l15, f2b(fmaxf(o[ct][r],0.f)));
    }
    __syncthreads();                          // (i)
    stg_write<64>(sm, tid, sreg);             // dw2t
    stg_issue<128>(ws + W_LRT, tid, sreg);    // lr gate 0
    __syncthreads();                          // (j)
    // P7: d2 = relu(d1@dw2 + db2) -> D2 (f32, overlays SA/SB — KOB done)
    {
      f32x4 d2[2];
      #pragma unroll
      for (int p = 0; p < 2; ++p) d2[p] = (f32x4){db2r[p],db2r[p],db2r[p],db2r[p]};
      #pragma unroll
      for (int kk = 0; kk < 4; ++kk) {
        bf16x8 av = ldfrag(sm, AB, rt*16+l15, kk, lch);
        #pragma unroll
        for (int p = 0; p < 2; ++p)
          d2[p] = MFMA16(av, ldfrag(sm, STG, c7b + p*16 + l15, kk, lch), d2[p]);
      }
      #pragma unroll
      for (int p = 0; p < 2; ++p) {
        f32x4 v;
        #pragma unroll
        for (int r = 0; r < 4; ++r) v[r] = fmaxf(d2[p][r], 0.f);
        *(f32x4*)(sm + SAB + (c7b + p*16 + l15)*272 + (rt*16+lch*4)*4) = v;
      }
    }
    __syncthreads();                          // (k)
    stg_write<128>(sm, tid, sreg);            // lr g0
    stg_issue<128>(ws + W_LRT + 32768, tid, sreg);
    // P8: bbox = sigmoid(d2@dw3 + db3) -> BX + outB (fp32, nt store)
    if (tid < 256) {
      const float* P = (const float*)(sm + PERMB);
      const int c8 = tid >> 6;
      float a = P[896 + c8];
      #pragma unroll 8
      for (int k = 0; k < 64; ++k)
        a = fmaf(*(const float*)(sm + SAB + k*272 + rS*4), P[640 + k*4 + c8], a);
      float bx = sigf(a);
      *(float*)(sm + BXB + c8*272 + rS*4) = bx;
      __builtin_nontemporal_store(bx, &outB[(((size_t)rbase + rS)*LL + st)*4 + c8]);
    }
    __syncthreads();                          // (l)
    // P9: gates (keras i,f,c,o)
    f32x4 a90[4], a91[4], a92[4], a93[4];
    #pragma unroll
    for (int r = 0; r < 4; ++r) {
      a90[r] = (f32x4){lbr[0]+lkr[0],lbr[0]+lkr[0],lbr[0]+lkr[0],lbr[0]+lkr[0]};
      a91[r] = (f32x4){lbr[1]+lkr[1],lbr[1]+lkr[1],lbr[1]+lkr[1],lbr[1]+lkr[1]};
      a92[r] = (f32x4){lbr[2]+lkr[2],lbr[2]+lkr[2],lbr[2]+lkr[2],lbr[2]+lkr[2]};
      a93[r] = (f32x4){lbr[3]+lkr[3],lbr[3]+lkr[3],lbr[3]+lkr[3],lbr[3]+lkr[3]};
    }
    #pragma unroll
    for (int kk = 0; kk < 4; ++kk) {          // gate 0
      bf16x8 bv = ldfrag(sm, STG, ju, kk, lch);
      #pragma unroll
      for (int r = 0; r < 4; ++r)
        a90[r] = MFMA16(ldfrag(sm, HB, r*16+l15, kk, lch), bv, a90[r]);
    }
    __syncthreads();
    stg_write<128>(sm, tid, sreg);            // lr g1
    stg_issue<128>(ws + W_LRT + 65536, tid, sreg);
    __syncthreads();
    #pragma unroll
    for (int kk = 0; kk < 4; ++kk) {          // gate 1
      bf16x8 bv = ldfrag(sm, STG, ju, kk, lch);
      #pragma unroll
      for (int r = 0; r < 4; ++r)
        a91[r] = MFMA16(ldfrag(sm, HB, r*16+l15, kk, lch), bv, a91[r]);
    }
    __syncthreads();
    stg_write<128>(sm, tid, sreg);            // lr g2
    stg_issue<128>(ws + W_LRT + 98304, tid, sreg);
    __syncthreads();
    #pragma unroll
    for (int kk = 0; kk < 4; ++kk) {          // gate 2
      bf16x8 bv = ldfrag(sm, STG, ju, kk, lch);
      #pragma unroll
      for (int r = 0; r < 4; ++r)
        a92[r] = MFMA16(ldfrag(sm, HB, r*16+l15, kk, lch), bv, a92[r]);
    }
    __syncthreads();
    stg_write<128>(sm, tid, sreg);            // lr g3
    stg_issue<128>(ws + W_CW5T, tid, sreg);   // next step's cw5t
    __syncthreads();
    #pragma unroll
    for (int kk = 0; kk < 4; ++kk) {          // gate 3
      bf16x8 bv = ldfrag(sm, STG, ju, kk, lch);
      #pragma unroll
      for (int r = 0; r < 4; ++r)
        a93[r] = MFMA16(ldfrag(sm, HB, r*16+l15, kk, lch), bv, a93[r]);
    }
    // bbox tail (fp32, K=4)
    #pragma unroll
    for (int rr = 0; rr < 4; ++rr)
      #pragma unroll
      for (int r = 0; r < 4; ++r) {
        const int row = rr*16 + lch*4 + r;
        #pragma unroll
        for (int k = 0; k < 4; ++k) {
          float bx = *(const float*)(sm + BXB + k*272 + row*4);
          a90[rr][r] = fmaf(bx, lkbr[k][0], a90[rr][r]);
          a91[rr][r] = fmaf(bx, lkbr[k][1], a91[rr][r]);
          a92[rr][r] = fmaf(bx, lkbr[k][2], a92[rr][r]);
          a93[rr][r] = fmaf(bx, lkbr[k][3], a93[rr][r]);
        }
      }
    __syncthreads();                          // (m)
    // LSTM elementwise; h -> HB
    #pragma unroll
    for (int rr = 0; rr < 4; ++rr)
      #pragma unroll
      for (int r = 0; r < 4; ++r) {
        float gi = sigf(a90[rr][r]);
        float gf = sigf(a91[rr][r]);
        float gg = tanhf_(a92[rr][r]);
        float go = sigf(a93[rr][r]);
        float cn = fmaf(gf, creg[rr][r], gi*gg);
        creg[rr][r] = cn;
        stb16(sm, HB, rr*16 + lch*4 + r, ju, f2b(go * tanhf_(cn)));
      }
  }
}

extern "C" void kernel_launch(void* const* d_in, const int* in_sizes, int n_in,
                              void* d_out, int out_size, void* d_ws, size_t ws_size,
                              hipStream_t stream)
{
  const float* ls  = (const float*)d_in[0];
  const float* bbin= (const float*)d_in[1];
  const float* eps = (const float*)d_in[2];
  const float* cw1=(const float*)d_in[3];  const float* cb1=(const float*)d_in[4];
  const float* cw2=(const float*)d_in[5];  const float* cb2=(const float*)d_in[6];
  const float* cw3=(const float*)d_in[7];  const float* cb3=(const float*)d_in[8];
  const float* cw4=(const float*)d_in[9];  const float* cb4=(const float*)d_in[10];
  const float* cw5=(const float*)d_in[11]; const float* cb5=(const float*)d_in[12];
  const float* cwo=(const float*)d_in[13]; const float* cbo=(const float*)d_in[14];
  const float* pw1=(const float*)d_in[15]; const float* pb1=(const float*)d_in[16];
  const float* pwm=(const float*)d_in[17]; const float* pbm=(const float*)d_in[18];
  const float* pwv=(const float*)d_in[19]; const float* pbv=(const float*)d_in[20];
  const float* ew1=(const float*)d_in[21]; const float* eb1=(const float*)d_in[22];
  const float* ew2=(const float*)d_in[23]; const float* eb2=(const float*)d_in[24];
  const float* ew3=(const float*)d_in[25]; const float* eb3=(const float*)d_in[26];
  const float* ewm=(const float*)d_in[27]; const float* ebm=(const float*)d_in[28];
  const float* ewv=(const float*)d_in[29]; const float* ebv=(const float*)d_in[30];
  const float* dw1=(const float*)d_in[31]; const float* db1=(const float*)d_in[32];
  const float* dw2=(const float*)d_in[33]; const float* db2=(const float*)d_in[34];
  const float* dw3=(const float*)d_in[35]; const float* db3=(const float*)d_in[36];
  const float* lk =(const float*)d_in[37]; const float* lr =(const float*)d_in[38];
  const float* lb =(const float*)d_in[39];

  char* ws = (char*)d_ws;
  float* outB = (float*)d_out;
  float* outK = outB + (size_t)BB*LL*4;

  hipFuncSetAttribute((const void*)vae_main, hipFuncAttributeMaxDynamicSharedMemorySize, LDS_BYTES);

  vae_pre<<<dim3(42), dim3(256), 0, stream>>>(cw2, cw3, cb3, cw4, cb4, cw5, cwo, pw1,
                                              ew2, ew3, eb2, eb3, dw1, dw2, lr, ws);
  vae_main<<<dim3(NBLK), dim3(NTHR), LDS_BYTES, stream>>>(
      ls, bbin, eps, cw1, cb1, cb2, cb5, cbo,
      pb1, pbm, pbv, pwm, pwv, ew1, eb1, ewm, ebm, ewv, ebv,
      db1, db2, dw3, db3, lk, lb, ws, outB, outK);
}